// Round 8
// baseline (451.917 us; speedup 1.0000x reference)
//
#include <hip/hip_runtime.h>
#include <hip/hip_bf16.h>
#include <math.h>

#define B 1024
#define D 512
#define KC 100000
#define MARGIN 0.3f
#define EPSSM 0.1f
#define NPANEL 391   // ceil(KC/256)

typedef __attribute__((ext_vector_type(8))) short bf16x8;
typedef __attribute__((ext_vector_type(4))) float f32x4;

__device__ __forceinline__ unsigned cvtpk(float lo, float hi) {
    union { __hip_bfloat162 h2; unsigned u; } cv;
    cv.h2 = __float22bfloat162_rn(make_float2(lo, hi));
    return cv.u;
}

__device__ __forceinline__ void async16(const void* g, void* l) {
    __builtin_amdgcn_global_load_lds((const __attribute__((address_space(1))) unsigned int*)g,
                                     (__attribute__((address_space(3))) unsigned int*)l,
                                     16, 0, 0);
}

#define VMCNT(n) asm volatile("s_waitcnt vmcnt(" #n ")" ::: "memory")
#define FENCE    asm volatile("" ::: "memory")

// ws float layout: [0,B) sumexp | [B,2B) lin = 0.9*t + 1e-6*sumlogit | [2B,3B) apbits | [3B,4B) anbits
// xp (bf16 packed x) at byte 16384, 1MB; wp (bf16 packed W) after, ~102.5MB. (== R4-proven ws need)

// ---------------- init workspace ----------------
__global__ void init_ws(float* ws) {
    int i = blockIdx.x * blockDim.x + threadIdx.x;
    if (i < 2 * B) ws[i] = 0.f;                                  // sumexp, lin
    else if (i < 3 * B) ((int*)ws)[i] = 0;                       // apbits = 0.0f
    else if (i < 4 * B) ((int*)ws)[i] = 0x7F800000;              // anbits = +inf
}

// ================= PREP: triplet + tlabel + pack_x + pack_w in one grid ===========
// blocks [0,256): triplet (row-group = bid>>1, j-half = bid&1)
// blocks [256,512): tlabel
// blocks [512,768): pack_x
// blocks [768, 768+25024): pack_w
__global__ __launch_bounds__(256) void prep_kernel(const float* __restrict__ x,
                                                   const float* __restrict__ W,
                                                   const float* __restrict__ bias,
                                                   const int* __restrict__ labels,
                                                   float* __restrict__ ws,
                                                   unsigned short* __restrict__ xp,
                                                   unsigned short* __restrict__ wp) {
    const int bid = blockIdx.x;
    const int tid = threadIdx.x;
    __shared__ float xs[8][D];
    __shared__ int labs[8];
    __shared__ float sqi[8];
    __shared__ float red_ap[8][4], red_an[8][4];

    if (bid >= 768) {
        // ---------- pack_w: inverse-mapped, coalesced 16B-unit writes ----------
        size_t oid = (size_t)(bid - 768) * 256 + tid;   // 0 .. 391*16*1024-1
        int region = (int)(oid >> 10);                  // (panel*8+u)*2+kh
        int p = (int)(oid & 1023);
        int panel = region >> 4;
        int rest = region & 15;
        int u = rest >> 1, kh = rest & 1;
        int prow = p >> 2;
        int u2 = (p & 3) ^ ((prow >> 1) & 3);
        int c = panel * 256 + prow;
        unsigned pv[4];
        if (c < KC) {
            const float* src = W + (size_t)c * D + u * 64 + kh * 32 + u2 * 8;
            f32x4 a = __builtin_nontemporal_load((const f32x4*)src);
            f32x4 b2 = __builtin_nontemporal_load((const f32x4*)(src + 4));
            pv[0] = cvtpk(a[0], a[1]);  pv[1] = cvtpk(a[2], a[3]);
            pv[2] = cvtpk(b2[0], b2[1]); pv[3] = cvtpk(b2[2], b2[3]);
        } else {
            pv[0] = pv[1] = pv[2] = pv[3] = 0u;
        }
        *(uint4*)(wp + ((size_t)region << 13) + (size_t)p * 8) = *(uint4*)pv;
        return;
    }
    if (bid >= 512) {
        // ---------- pack_x (R6 geometry: region (rblk,u,h) 16KB, unit swizzled) ----------
        int gid = (bid - 512) * 256 + tid;   // 0..65535
        int row = gid >> 6;
        int rest = gid & 63;
        int u = rest >> 3, ku = rest & 7;
        int rblk = row >> 8, h = (row >> 7) & 1, rloc = row & 127;
        const float* src = x + (size_t)row * D + u * 64 + ku * 8;
        f32x4 a = *(const f32x4*)src;
        f32x4 b2 = *(const f32x4*)(src + 4);
        unsigned pv[4] = { cvtpk(a[0], a[1]), cvtpk(a[2], a[3]), cvtpk(b2[0], b2[1]), cvtpk(b2[2], b2[3]) };
        size_t off = ((size_t)((rblk * 8 + u) * 2 + h) << 13) + (size_t)(rloc * 8 + (ku ^ (rloc & 7))) * 8;
        *(uint4*)(xp + off) = *(uint4*)pv;
        return;
    }
    if (bid >= 256) {
        // ---------- tlabel: lin[row] += 0.9 * (x_row . W[label] + bias[label]) ----------
        int wid = tid >> 6, lane = tid & 63;
        int row = (bid - 256) * 4 + wid;
        int lab = labels[row];
        const float* xr = x + (size_t)row * D;
        const float* wr = W + (size_t)lab * D;
        float dsum = 0.f;
#pragma unroll
        for (int u = 0; u < 2; ++u) {
            int k = (lane * 2 + u) * 4;
            float4 a = *(const float4*)&xr[k];
            float4 w = *(const float4*)&wr[k];
            dsum += a.x * w.x + a.y * w.y + a.z * w.z + a.w * w.w;
        }
        for (int o = 32; o >= 1; o >>= 1) dsum += __shfl_xor(dsum, o);
        if (lane == 0) atomicAdd(&ws[B + row], (1.f - EPSSM) * (dsum + bias[lab]));
        return;
    }

    // ---------- triplet: batch-hard over a 512-j half, atomic max/min merge ----------
    const int row0 = (bid >> 1) * 8;
    const int jbase = (bid & 1) * 512;
    for (int f = tid; f < 8 * (D / 4); f += 256) {
        int r = f / (D / 4);
        int p = f % (D / 4);
        *(float4*)&xs[r][p * 4] = *(const float4*)&x[(size_t)(row0 + r) * D + p * 4];
    }
    if (tid < 8) labs[tid] = labels[row0 + tid];
    __syncthreads();
    if (tid < 8) {
        float s = 0.f;
        for (int k = 0; k < D; ++k) s += xs[tid][k] * xs[tid][k];
        sqi[tid] = s;
    }
    __syncthreads();

    float ap[8], an[8];
#pragma unroll
    for (int r = 0; r < 8; ++r) { ap[r] = -INFINITY; an[r] = INFINITY; }

    for (int j = jbase + tid; j < jbase + 512; j += 256) {
        int labj = labels[j];
        float dot[8];
        float sqj = 0.f;
#pragma unroll
        for (int r = 0; r < 8; ++r) dot[r] = 0.f;
        for (int kc = 0; kc < D; kc += 32) {
            float4 xj[8];
#pragma unroll
            for (int u = 0; u < 8; ++u) xj[u] = *(const float4*)&x[(size_t)j * D + kc + u * 4];
#pragma unroll
            for (int u = 0; u < 8; ++u)
                sqj += xj[u].x * xj[u].x + xj[u].y * xj[u].y + xj[u].z * xj[u].z + xj[u].w * xj[u].w;
#pragma unroll
            for (int r = 0; r < 8; ++r) {
                float d = 0.f;
#pragma unroll
                for (int u = 0; u < 8; ++u) {
                    const float4 a = *(const float4*)&xs[r][kc + u * 4];
                    d += a.x * xj[u].x + a.y * xj[u].y + a.z * xj[u].z + a.w * xj[u].w;
                }
                dot[r] += d;
            }
        }
#pragma unroll
        for (int r = 0; r < 8; ++r) {
            float d2 = sqi[r] + sqj - 2.f * dot[r];
            float dist = sqrtf(fmaxf(d2, 1e-12f));
            if (labj == labs[r]) ap[r] = fmaxf(ap[r], dist);
            else an[r] = fminf(an[r], dist);
        }
    }
#pragma unroll
    for (int r = 0; r < 8; ++r) {
        for (int o = 32; o >= 1; o >>= 1) {
            ap[r] = fmaxf(ap[r], __shfl_xor(ap[r], o));
            an[r] = fminf(an[r], __shfl_xor(an[r], o));
        }
    }
    int wid = tid >> 6;
    if ((tid & 63) == 0) {
#pragma unroll
        for (int r = 0; r < 8; ++r) { red_ap[r][wid] = ap[r]; red_an[r][wid] = an[r]; }
    }
    __syncthreads();
    if (tid < 8) {
        float a = -INFINITY, n = INFINITY;
#pragma unroll
        for (int w = 0; w < 4; ++w) { a = fmaxf(a, red_ap[tid][w]); n = fminf(n, red_an[tid][w]); }
        a = fmaxf(a, 0.f);                      // dists >= 0; keeps int-max trick valid
        int* apbits = (int*)(ws + 2 * B);
        int* anbits = (int*)(ws + 3 * B);
        atomicMax(&apbits[row0 + tid], __float_as_int(a));
        atomicMin(&anbits[row0 + tid], __float_as_int(n));
    }
}

// ============ persistent 8-phase 256x256xBK64 bf16 MFMA GEMM ============
// grid=256 (1 block/CU), 512 thr (8 waves 2Mx4N). Block (e=bid&7, pi, rr) processes
// tasks j: panel c=(j*8+pi)*8+e (same XCD -> 8 panels/round, 2MB L2), row-block rr
// fixed -> LDS-resident per-row accumulators across tasks, atomics once at end.
// LDS: 8 staging half-slots x 16KB = 128KB + 8KB scratch. Verified vmcnt ledger:
// ph0: VMCNT(1) (u==0: VMCNT(5), absorbs 4 bias prefetch loads); ph2: VMCNT(2);
// last tile overall: ph2 VMCNT(0). Stage order per tile: A0,A1,B0,B1 (next tile).
__global__ __launch_bounds__(512, 2) void ce_gemm_pp(const unsigned short* __restrict__ xp,
                                                     const unsigned short* __restrict__ wp,
                                                     const float* __restrict__ bias,
                                                     float* __restrict__ ws) {
    const int b = blockIdx.x;
    const int e = b & 7;                   // hw XCD (round-robin dispatch)
    const int m8 = b >> 3;
    const int pi = m8 >> 2, rr = m8 & 3;   // panel-slot, row-block (fixed)
    const int ntask = ((390 - e - 8 * pi) / 64) + 1;   // 6 or 7, exact cover of 391x4
    const int rowbase = rr * 256;

    extern __shared__ unsigned short lds[];   // staging 65536 ushorts + scratch
    float* redE = (float*)(lds + 65536);      // [256][4]
    float* redL = redE + 1024;                // [256][4]

    const int tid = threadIdx.x;
    const int lane = tid & 63;
    const int wid = tid >> 6;
    const int wm = wid >> 2, wn = wid & 3;
    const int q = lane >> 4, l15 = lane & 15;

    for (int i = tid; i < 2048; i += 512) redE[i] = 0.f;   // zeros redE+redL
    __syncthreads();

    f32x4 acc[8][4];
#pragma unroll
    for (int m = 0; m < 8; ++m)
#pragma unroll
        for (int n = 0; n < 4; ++n) acc[m][n] = (f32x4){0.f, 0.f, 0.f, 0.f};

#define STAGE_A(kt_, h_) {                                                            \
        const unsigned short* g = xp + ((size_t)((rr * 8 + ((kt_) & 7)) * 2 + (h_)) << 13); \
        unsigned short* l = &lds[((((kt_) & 1) * 4 + (h_)) << 13)];                   \
        async16(g + tid * 8, l + tid * 8);                                            \
        async16(g + 4096 + tid * 8, l + 4096 + tid * 8); }
#define STAGE_B(c_, kt_, h_) {                                                        \
        const unsigned short* g = wp + ((size_t)(((c_) * 8 + ((kt_) & 7)) * 2 + (h_)) << 13); \
        unsigned short* l = &lds[((((kt_) & 1) * 4 + 2 + (h_)) << 13)];               \
        async16(g + tid * 8, l + tid * 8);                                            \
        async16(g + 4096 + tid * 8, l + 4096 + tid * 8); }
#define READ_A(mg_, ks_) {                                                            \
        const unsigned short* sA = &lds[(((u & 1) * 4 + wm) << 13)];                  \
        _Pragma("unroll") for (int mf = 0; mf < 4; ++mf) {                            \
            int rloc = ((mg_) * 4 + mf) * 16 + l15;                                   \
            int unit = rloc * 8 + (((ks_) * 4 + q) ^ (rloc & 7));                     \
            af[mf] = *(const bf16x8*)&sA[unit * 8]; } }
#define READ_B(ks_) {                                                                 \
        const unsigned short* sB = &lds[(((u & 1) * 4 + 2 + (ks_)) << 13)];           \
        _Pragma("unroll") for (int nf = 0; nf < 4; ++nf) {                            \
            int row = wn * 64 + nf * 16 + l15;                                        \
            int unit = row * 4 + (q ^ ((row >> 1) & 3));                              \
            bfr[nf] = *(const bf16x8*)&sB[unit * 8]; } }
#define MFMAC(mg_) {                                                                  \
        __builtin_amdgcn_s_setprio(1);                                                \
        _Pragma("unroll") for (int mf = 0; mf < 4; ++mf)                              \
        _Pragma("unroll") for (int nf = 0; nf < 4; ++nf)                              \
            acc[(mg_) * 4 + mf][nf] = __builtin_amdgcn_mfma_f32_16x16x32_bf16(        \
                af[mf], bfr[nf], acc[(mg_) * 4 + mf][nf], 0, 0, 0);                   \
        __builtin_amdgcn_s_setprio(0); }

    int c = pi * 8 + e;   // task j=0 panel
    float biasreg[4];
#pragma unroll
    for (int n = 0; n < 4; ++n) {
        int cc = c * 256 + wn * 64 + n * 16 + l15;
        biasreg[n] = bias[cc < KC ? cc : KC - 1];
    }
    // prologue: stage tile 0 fully (parity 0)
    STAGE_A(0, 0); STAGE_A(0, 1); STAGE_B(c, 0, 0); STAGE_B(c, 0, 1);
    VMCNT(2);
    __builtin_amdgcn_s_barrier(); FENCE;

    bf16x8 af[4], bfr[4];
    for (int j = 0; j < ntask; ++j) {
        const bool lastTask = (j == ntask - 1);
        const int cnext = c + 64;
#pragma unroll
        for (int u = 0; u < 8; ++u) {
            const bool lastU = (u == 7);
            const bool stage = !(lastU && lastTask);
            const int cs = lastU ? cnext : c;
            // ---- ph0 ----
            if (u == 0) { VMCNT(5); } else { VMCNT(1); }
            READ_A(0, 0); READ_B(0);
            if (stage) STAGE_A(u + 1, 0);
            __builtin_amdgcn_s_barrier(); FENCE;
            MFMAC(0);
            __builtin_amdgcn_s_barrier(); FENCE;
            // ---- ph1 ----
            READ_A(1, 0);
            if (stage) STAGE_A(u + 1, 1);
            __builtin_amdgcn_s_barrier(); FENCE;
            MFMAC(1);
            __builtin_amdgcn_s_barrier(); FENCE;
            // ---- ph2 ----
            if (lastU && lastTask) { VMCNT(0); } else { VMCNT(2); }
            READ_A(0, 1); READ_B(1);
            if (stage) STAGE_B(cs, u + 1, 0);
            __builtin_amdgcn_s_barrier(); FENCE;
            MFMAC(0);
            __builtin_amdgcn_s_barrier(); FENCE;
            // ---- ph3 ----
            READ_A(1, 1);
            if (stage) STAGE_B(cs, u + 1, 1);
            __builtin_amdgcn_s_barrier(); FENCE;
            MFMAC(1);
            __builtin_amdgcn_s_barrier(); FENCE;
        }
        // ---- per-task epilogue: VALU + private LDS accumulators only ----
#pragma unroll
        for (int m = 0; m < 8; ++m) {
#pragma unroll
            for (int r2 = 0; r2 < 4; ++r2) {
                float pe = 0.f, pl = 0.f;
#pragma unroll
                for (int n = 0; n < 4; ++n) {
                    int cc = c * 256 + wn * 64 + n * 16 + l15;
                    if (cc < KC) {
                        float lg = acc[m][n][r2] + biasreg[n];
                        pe += __expf(lg);
                        pl += lg;
                    }
                }
#pragma unroll
                for (int o = 1; o < 16; o <<= 1) {
                    pe += __shfl_xor(pe, o);
                    pl += __shfl_xor(pl, o);
                }
                if (l15 == 0) {
                    int rowl = wm * 128 + m * 16 + q * 4 + r2;
                    redE[rowl * 4 + wn] += pe;
                    redL[rowl * 4 + wn] += pl;
                }
            }
        }
#pragma unroll
        for (int m = 0; m < 8; ++m)
#pragma unroll
            for (int n = 0; n < 4; ++n) acc[m][n] = (f32x4){0.f, 0.f, 0.f, 0.f};
        if (!lastTask) {
            c = cnext;
#pragma unroll
            for (int n = 0; n < 4; ++n) {
                int cc = c * 256 + wn * 64 + n * 16 + l15;
                biasreg[n] = bias[cc < KC ? cc : KC - 1];
            }
        }
    }
#undef STAGE_A
#undef STAGE_B
#undef READ_A
#undef READ_B
#undef MFMAC

    // ---- final: cross-wave reduce + one atomic pair per row ----
    __syncthreads();
    if (tid < 256) {
        float se = redE[tid * 4] + redE[tid * 4 + 1] + redE[tid * 4 + 2] + redE[tid * 4 + 3];
        float sl = redL[tid * 4] + redL[tid * 4 + 1] + redL[tid * 4 + 2] + redL[tid * 4 + 3];
        atomicAdd(&ws[rowbase + tid], se);                                // sumexp
        atomicAdd(&ws[B + rowbase + tid], (EPSSM / (float)KC) * sl);      // lin += 1e-6 * S
    }
}

// ---------------- final combine ----------------
__global__ __launch_bounds__(1024) void final_kernel(const float* __restrict__ ws,
                                                     float* __restrict__ out) {
    const float* sumexp = ws;
    const float* lin = ws + B;
    const int* apbits = (const int*)(ws + 2 * B);
    const int* anbits = (const int*)(ws + 3 * B);
    int i = threadIdx.x;
    float ce = logf(sumexp[i]) - lin[i];
    float ap = __int_as_float(apbits[i]);
    float an = __int_as_float(anbits[i]);
    float v = ce + fmaxf(ap - an + MARGIN, 0.f);   // WEIGHT_T = WEIGHT_X = 1
    for (int o = 32; o >= 1; o >>= 1) v += __shfl_xor(v, o);
    __shared__ float red[16];
    int wid = threadIdx.x >> 6, lane = threadIdx.x & 63;
    if (lane == 0) red[wid] = v;
    __syncthreads();
    if (threadIdx.x == 0) {
        float s = 0.f;
#pragma unroll
        for (int w = 0; w < 16; ++w) s += red[w];
        out[0] = s / (float)B;
    }
}

extern "C" void kernel_launch(void* const* d_in, const int* in_sizes, int n_in,
                              void* d_out, int out_size, void* d_ws, size_t ws_size,
                              hipStream_t stream) {
    const float* x = (const float*)d_in[0];
    const float* W = (const float*)d_in[1];
    const float* bias = (const float*)d_in[2];
    const int* labels = (const int*)d_in[3];
    float* out = (float*)d_out;
    float* ws = (float*)d_ws;

    unsigned short* xp = (unsigned short*)((char*)d_ws + 16384);
    unsigned short* wp = xp + (size_t)B * D;   // 391*16 regions * 8192 ushorts

    init_ws<<<16, 256, 0, stream>>>(ws);
    prep_kernel<<<768 + 25024, 256, 0, stream>>>(x, W, bias, labels, ws, xp, wp);
    ce_gemm_pp<<<256, 512, 139264, stream>>>(xp, wp, bias, ws);
    final_kernel<<<1, 1024, 0, stream>>>(ws, out);
}

// Round 10
// 381.427 us; speedup vs baseline: 1.1848x; 1.1848x over previous
//
#include <hip/hip_runtime.h>
#include <hip/hip_bf16.h>
#include <math.h>

#define B 1024
#define D 512
#define KC 100000
#define MARGIN 0.3f
#define EPSSM 0.1f

typedef __attribute__((ext_vector_type(8))) short bf16x8;
typedef __attribute__((ext_vector_type(4))) float f32x4;

__device__ __forceinline__ unsigned cvtpk(float lo, float hi) {
    union { __hip_bfloat162 h2; unsigned u; } cv;
    cv.h2 = __float22bfloat162_rn(make_float2(lo, hi));
    return cv.u;
}

__device__ __forceinline__ void async16(const void* g, void* l) {
    __builtin_amdgcn_global_load_lds((const __attribute__((address_space(1))) unsigned int*)g,
                                     (__attribute__((address_space(3))) unsigned int*)l,
                                     16, 0, 0);
}

#define VMCNT(n) asm volatile("s_waitcnt vmcnt(" #n ")" ::: "memory")
#define FENCE    asm volatile("" ::: "memory")

// ws float layout: [0,B) sumexp | [B,2B) lin = 0.9*t + (eps/K)*sumlogit | [2B,3B) apbits | [3B,4B) anbits
// xp (packed bf16 x) at byte 16384, 1MB; wp (packed bf16 W) after, ~102.5MB.

// ---------------- init workspace ----------------
__global__ void init_ws(float* ws) {
    int i = blockIdx.x * blockDim.x + threadIdx.x;
    if (i < 2 * B) ws[i] = 0.f;
    else if (i < 3 * B) ((int*)ws)[i] = 0;              // apbits = 0.0f
    else if (i < 4 * B) ((int*)ws)[i] = 0x7F800000;     // anbits = +inf
}

// ================= PREP: triplet + tlabel + pack_x + pack_w in one grid ===========
// blocks [0,256): triplet; [256,512): tlabel; [512,768): pack_x; [768,768+25024): pack_w
__global__ __launch_bounds__(256) void prep_kernel(const float* __restrict__ x,
                                                   const float* __restrict__ W,
                                                   const float* __restrict__ bias,
                                                   const int* __restrict__ labels,
                                                   float* __restrict__ ws,
                                                   unsigned short* __restrict__ xp,
                                                   unsigned short* __restrict__ wp) {
    const int bid = blockIdx.x;
    const int tid = threadIdx.x;
    __shared__ float xs[8][D];
    __shared__ int labs[8];
    __shared__ float sqi[8];
    __shared__ float red_ap[8][4], red_an[8][4];

    if (bid >= 768) {
        // pack_w: region (panel*8+kt)*2+kh = 16KB = [256 rows][4 units], swz (prow>>1)&3
        size_t oid = (size_t)(bid - 768) * 256 + tid;
        int region = (int)(oid >> 10);
        int p = (int)(oid & 1023);
        int panel = region >> 4;
        int rest = region & 15;
        int u = rest >> 1, kh = rest & 1;
        int prow = p >> 2;
        int u2 = (p & 3) ^ ((prow >> 1) & 3);
        int c = panel * 256 + prow;
        unsigned pv[4];
        if (c < KC) {
            const float* src = W + (size_t)c * D + u * 64 + kh * 32 + u2 * 8;
            f32x4 a = __builtin_nontemporal_load((const f32x4*)src);
            f32x4 b2 = __builtin_nontemporal_load((const f32x4*)(src + 4));
            pv[0] = cvtpk(a[0], a[1]);  pv[1] = cvtpk(a[2], a[3]);
            pv[2] = cvtpk(b2[0], b2[1]); pv[3] = cvtpk(b2[2], b2[3]);
        } else {
            pv[0] = pv[1] = pv[2] = pv[3] = 0u;
        }
        *(uint4*)(wp + ((size_t)region << 13) + (size_t)p * 8) = *(uint4*)pv;
        return;
    }
    if (bid >= 512) {
        // pack_x: region (rblk*8+kt)*2+kh = 16KB = [256 rows][4 units], swz (rloc>>1)&3
        int gid = (bid - 512) * 256 + tid;   // 1024 rows * 64 units
        int row = gid >> 6;
        int rest = gid & 63;
        int kt = rest >> 3, kh = (rest >> 2) & 1, ku = rest & 3;
        int rblk = row >> 8, rloc = row & 255;
        const float* src = x + (size_t)row * D + kt * 64 + kh * 32 + ku * 8;
        f32x4 a = *(const f32x4*)src;
        f32x4 b2 = *(const f32x4*)(src + 4);
        unsigned pv[4] = { cvtpk(a[0], a[1]), cvtpk(a[2], a[3]), cvtpk(b2[0], b2[1]), cvtpk(b2[2], b2[3]) };
        size_t off = ((size_t)((rblk * 8 + kt) * 2 + kh) << 13) + (size_t)(rloc * 4 + (ku ^ ((rloc >> 1) & 3))) * 8;
        *(uint4*)(xp + off) = *(uint4*)pv;
        return;
    }
    if (bid >= 256) {
        // tlabel
        int wid = tid >> 6, lane = tid & 63;
        int row = (bid - 256) * 4 + wid;
        int lab = labels[row];
        const float* xr = x + (size_t)row * D;
        const float* wr = W + (size_t)lab * D;
        float dsum = 0.f;
#pragma unroll
        for (int u = 0; u < 2; ++u) {
            int k = (lane * 2 + u) * 4;
            float4 a = *(const float4*)&xr[k];
            float4 w = *(const float4*)&wr[k];
            dsum += a.x * w.x + a.y * w.y + a.z * w.z + a.w * w.w;
        }
        for (int o = 32; o >= 1; o >>= 1) dsum += __shfl_xor(dsum, o);
        if (lane == 0) atomicAdd(&ws[B + row], (1.f - EPSSM) * (dsum + bias[lab]));
        return;
    }

    // triplet: batch-hard over a 512-j half, atomic bitwise max/min merge
    const int row0 = (bid >> 1) * 8;
    const int jbase = (bid & 1) * 512;
    for (int f = tid; f < 8 * (D / 4); f += 256) {
        int r = f / (D / 4);
        int p = f % (D / 4);
        *(float4*)&xs[r][p * 4] = *(const float4*)&x[(size_t)(row0 + r) * D + p * 4];
    }
    if (tid < 8) labs[tid] = labels[row0 + tid];
    __syncthreads();
    if (tid < 8) {
        float s = 0.f;
        for (int k = 0; k < D; ++k) s += xs[tid][k] * xs[tid][k];
        sqi[tid] = s;
    }
    __syncthreads();

    float ap[8], an[8];
#pragma unroll
    for (int r = 0; r < 8; ++r) { ap[r] = -INFINITY; an[r] = INFINITY; }

    for (int j = jbase + tid; j < jbase + 512; j += 256) {
        int labj = labels[j];
        float dot[8];
        float sqj = 0.f;
#pragma unroll
        for (int r = 0; r < 8; ++r) dot[r] = 0.f;
        for (int kc = 0; kc < D; kc += 32) {
            float4 xj[8];
#pragma unroll
            for (int u = 0; u < 8; ++u) xj[u] = *(const float4*)&x[(size_t)j * D + kc + u * 4];
#pragma unroll
            for (int u = 0; u < 8; ++u)
                sqj += xj[u].x * xj[u].x + xj[u].y * xj[u].y + xj[u].z * xj[u].z + xj[u].w * xj[u].w;
#pragma unroll
            for (int r = 0; r < 8; ++r) {
                float d = 0.f;
#pragma unroll
                for (int u = 0; u < 8; ++u) {
                    const float4 a = *(const float4*)&xs[r][kc + u * 4];
                    d += a.x * xj[u].x + a.y * xj[u].y + a.z * xj[u].z + a.w * xj[u].w;
                }
                dot[r] += d;
            }
        }
#pragma unroll
        for (int r = 0; r < 8; ++r) {
            float d2 = sqi[r] + sqj - 2.f * dot[r];
            float dist = sqrtf(fmaxf(d2, 1e-12f));
            if (labj == labs[r]) ap[r] = fmaxf(ap[r], dist);
            else an[r] = fminf(an[r], dist);
        }
    }
#pragma unroll
    for (int r = 0; r < 8; ++r) {
        for (int o = 32; o >= 1; o >>= 1) {
            ap[r] = fmaxf(ap[r], __shfl_xor(ap[r], o));
            an[r] = fminf(an[r], __shfl_xor(an[r], o));
        }
    }
    int wid = tid >> 6;
    if ((tid & 63) == 0) {
#pragma unroll
        for (int r = 0; r < 8; ++r) { red_ap[r][wid] = ap[r]; red_an[r][wid] = an[r]; }
    }
    __syncthreads();
    if (tid < 8) {
        float a = -INFINITY, n = INFINITY;
#pragma unroll
        for (int w = 0; w < 4; ++w) { a = fmaxf(a, red_ap[tid][w]); n = fminf(n, red_an[tid][w]); }
        a = fmaxf(a, 0.f);
        int* apbits = (int*)(ws + 2 * B);
        int* anbits = (int*)(ws + 3 * B);
        atomicMax(&apbits[row0 + tid], __float_as_int(a));
        atomicMin(&anbits[row0 + tid], __float_as_int(n));
    }
}

// ============ persistent 256x256xBK64 GEMM, derived-wait pipeline ============
// grid=256 (1/CU), 512 thr (8 waves 2Mx4N). Block (e=bid&7, s, rr): fixed row-block
// rr, panel window [s*NJ/8,(s+1)*NJ/8) of its XCD's panels c=e+8j. Group stream per
// tile: A_kh0,B_kh0 (half H0) then A_kh1,B_kh1 (H1); each group read exactly 1 tile
// after issue. Steady state: 4 groups (8 ops) in flight -> uniform VMCNT(4) before
// each half's barrier; drain VMCNT(0) only at the very end. Per-task epilogue
// accumulates into [256][4] LDS slots (one per wave-column wn -> RACE-FREE, the R9
// bug was a single shared slot). Atomics once at kernel end.
__global__ __launch_bounds__(512, 1) void ce_gemm_v(const unsigned short* __restrict__ xp,
                                                    const unsigned short* __restrict__ wp,
                                                    const float* __restrict__ bias,
                                                    float* __restrict__ ws) {
    const int b = blockIdx.x;
    const int e = b & 7;
    const int slot = b >> 3;
    const int s = slot >> 2, rr = slot & 3;
    const int NJ = (e < 7) ? 49 : 48;
    const int jstart = (s * NJ) >> 3;
    const int jend = ((s + 1) * NJ) >> 3;
    const int ntask = jend - jstart;
    const int rowbase = rr * 256;

    extern __shared__ unsigned short lds[];     // 8 slots x 8192 ushorts = 128KB staging
    float* redE = (float*)(lds + 65536);        // [256][4]  (per-wn slot: race-free)
    float* redL = redE + 1024;                  // [256][4]
    float* biasL = redL + 1024;                 // [7][256]

    const int tid = threadIdx.x;
    const int lane = tid & 63;
    const int wid = tid >> 6;
    const int wm = wid >> 2, wn = wid & 3;      // 2M x 4N; wave tile 128x64
    const int q = lane >> 4, l15 = lane & 15;

    for (int i = tid; i < 2048; i += 512) redE[i] = 0.f;   // zero redE+redL
    for (int idx = tid; idx < ntask * 256; idx += 512) {
        int jj = idx >> 8, col = idx & 255;
        int cc = (e + 8 * (jstart + jj)) * 256 + col;
        biasL[idx] = bias[cc < KC ? cc : KC - 1];
    }
    __syncthreads();   // bias loads drained (value-dep) before the counted stream

    f32x4 acc[8][4];
#pragma unroll
    for (int m = 0; m < 8; ++m)
#pragma unroll
        for (int n = 0; n < 4; ++n) acc[m][n] = (f32x4){0.f, 0.f, 0.f, 0.f};

    // slots: parity*4 + {0:A_kh0, 1:B_kh0, 2:A_kh1, 3:B_kh1}
#define SLOT(par_, g_) (&lds[(((par_) * 4 + (g_)) << 13)])
#define STAGE_A(par_, kt_, kh_) {                                                  \
        const unsigned short* g = xp + ((size_t)((rr * 8 + (kt_)) * 2 + (kh_)) << 13); \
        unsigned short* l = SLOT(par_, (kh_) * 2);                                 \
        async16(g + tid * 8, l + tid * 8);                                         \
        async16(g + 4096 + tid * 8, l + 4096 + tid * 8); }
#define STAGE_B(par_, c_, kt_, kh_) {                                              \
        const unsigned short* g = wp + ((size_t)(((c_) * 8 + (kt_)) * 2 + (kh_)) << 13); \
        unsigned short* l = SLOT(par_, (kh_) * 2 + 1);                             \
        async16(g + tid * 8, l + tid * 8);                                         \
        async16(g + 4096 + tid * 8, l + 4096 + tid * 8); }
#define READ_A(mg_, ks_, par_) {                                                   \
        const unsigned short* sA = SLOT(par_, (ks_) * 2);                          \
        _Pragma("unroll") for (int mf = 0; mf < 4; ++mf) {                         \
            int rloc = wm * 128 + ((mg_) * 4 + mf) * 16 + l15;                     \
            int unit = rloc * 4 + (q ^ ((rloc >> 1) & 3));                         \
            af[mf] = *(const bf16x8*)&sA[unit * 8]; } }
#define READ_B(ks_, par_) {                                                        \
        const unsigned short* sB = SLOT(par_, (ks_) * 2 + 1);                      \
        _Pragma("unroll") for (int nf = 0; nf < 4; ++nf) {                         \
            int row = wn * 64 + nf * 16 + l15;                                     \
            int unit = row * 4 + (q ^ ((row >> 1) & 3));                           \
            bfr[nf] = *(const bf16x8*)&sB[unit * 8]; } }
#define MFMAC(mg_) {                                                               \
        __builtin_amdgcn_s_setprio(1);                                             \
        _Pragma("unroll") for (int mf = 0; mf < 4; ++mf)                           \
        _Pragma("unroll") for (int nf = 0; nf < 4; ++nf)                           \
            acc[(mg_) * 4 + mf][nf] = __builtin_amdgcn_mfma_f32_16x16x32_bf16(     \
                af[mf], bfr[nf], acc[(mg_) * 4 + mf][nf], 0, 0, 0);                \
        __builtin_amdgcn_s_setprio(0); }

    int c = e + 8 * jstart;
    // prologue: tile 0's 4 groups in stream order A0,B0,A1,B1 (parity 0)
    STAGE_A(0, 0, 0); STAGE_B(0, c, 0, 0); STAGE_A(0, 0, 1); STAGE_B(0, c, 0, 1);

    bf16x8 af[4], bfr[4];
    for (int j = 0; j < ntask; ++j) {
        const bool lastT = (j == ntask - 1);
        const int cn = c + 8;
#pragma unroll
        for (int u = 0; u < 8; ++u) {
            const int par = u & 1, npar = par ^ 1;
            const bool lastu = (u == 7);
            const bool dostage = !(lastu && lastT);
            const int kn = lastu ? 0 : u + 1;
            const int cs = lastu ? cn : c;
            // ---- half H0 (ks=0) ----
            VMCNT(4);
            __builtin_amdgcn_s_barrier(); FENCE;
            READ_A(0, 0, par); READ_B(0, par);
            if (dostage) STAGE_A(npar, kn, 0);
            MFMAC(0);
            READ_A(1, 0, par);
            if (dostage) STAGE_B(npar, cs, kn, 0);
            MFMAC(1);
            // ---- half H1 (ks=1) ----
            if (lastu && lastT) { VMCNT(0); } else { VMCNT(4); }
            __builtin_amdgcn_s_barrier(); FENCE;
            READ_A(0, 1, par); READ_B(1, par);
            if (dostage) STAGE_A(npar, kn, 1);
            MFMAC(0);
            READ_A(1, 1, par);
            if (dostage) STAGE_B(npar, cs, kn, 1);
            MFMAC(1);
        }

        // ---- per-task epilogue: VALU + LDS only, per-wn slot (race-free) ----
        float biasv[4];
#pragma unroll
        for (int n = 0; n < 4; ++n) biasv[n] = biasL[j * 256 + wn * 64 + n * 16 + l15];
#pragma unroll
        for (int m = 0; m < 8; ++m) {
#pragma unroll
            for (int r2 = 0; r2 < 4; ++r2) {
                float pe = 0.f, pl = 0.f;
#pragma unroll
                for (int n = 0; n < 4; ++n) {
                    int cc = c * 256 + wn * 64 + n * 16 + l15;
                    if (cc < KC) {
                        float lg = acc[m][n][r2] + biasv[n];
                        pe += __expf(lg);
                        pl += lg;
                    }
                }
#pragma unroll
                for (int o = 1; o < 16; o <<= 1) {
                    pe += __shfl_xor(pe, o);
                    pl += __shfl_xor(pl, o);
                }
                if (l15 == 0) {
                    int rowl = wm * 128 + m * 16 + q * 4 + r2;
                    redE[rowl * 4 + wn] += pe;
                    redL[rowl * 4 + wn] += pl;
                }
            }
        }
#pragma unroll
        for (int m = 0; m < 8; ++m)
#pragma unroll
            for (int n = 0; n < 4; ++n) acc[m][n] = (f32x4){0.f, 0.f, 0.f, 0.f};
        c = cn;
    }
#undef SLOT
#undef STAGE_A
#undef STAGE_B
#undef READ_A
#undef READ_B
#undef MFMAC

    // ---- final: reduce 4 wn-slots, one atomic pair per row ----
    __syncthreads();
    if (tid < 256) {
        float se = redE[tid * 4] + redE[tid * 4 + 1] + redE[tid * 4 + 2] + redE[tid * 4 + 3];
        float sl = redL[tid * 4] + redL[tid * 4 + 1] + redL[tid * 4 + 2] + redL[tid * 4 + 3];
        atomicAdd(&ws[rowbase + tid], se);
        atomicAdd(&ws[B + rowbase + tid], (EPSSM / (float)KC) * sl);
    }
}

// ---------------- final combine ----------------
__global__ __launch_bounds__(1024) void final_kernel(const float* __restrict__ ws,
                                                     float* __restrict__ out) {
    const float* sumexp = ws;
    const float* lin = ws + B;
    const int* apbits = (const int*)(ws + 2 * B);
    const int* anbits = (const int*)(ws + 3 * B);
    int i = threadIdx.x;
    float ce = logf(sumexp[i]) - lin[i];
    float ap = __int_as_float(apbits[i]);
    float an = __int_as_float(anbits[i]);
    float v = ce + fmaxf(ap - an + MARGIN, 0.f);
    for (int o = 32; o >= 1; o >>= 1) v += __shfl_xor(v, o);
    __shared__ float red[16];
    int wid = threadIdx.x >> 6, lane = threadIdx.x & 63;
    if (lane == 0) red[wid] = v;
    __syncthreads();
    if (threadIdx.x == 0) {
        float s = 0.f;
#pragma unroll
        for (int w = 0; w < 16; ++w) s += red[w];
        out[0] = s / (float)B;
    }
}

extern "C" void kernel_launch(void* const* d_in, const int* in_sizes, int n_in,
                              void* d_out, int out_size, void* d_ws, size_t ws_size,
                              hipStream_t stream) {
    const float* x = (const float*)d_in[0];
    const float* W = (const float*)d_in[1];
    const float* bias = (const float*)d_in[2];
    const int* labels = (const int*)d_in[3];
    float* out = (float*)d_out;
    float* ws = (float*)d_ws;

    unsigned short* xp = (unsigned short*)((char*)d_ws + 16384);
    unsigned short* wp = xp + (size_t)B * D;

    init_ws<<<16, 256, 0, stream>>>(ws);
    prep_kernel<<<768 + 25024, 256, 0, stream>>>(x, W, bias, labels, ws, xp, wp);
    // dynamic LDS: 128KB staging + 8KB red + 7KB bias = 146432 B
    ce_gemm_v<<<256, 512, 146432, stream>>>(xp, wp, bias, ws);
    final_kernel<<<1, 1024, 0, stream>>>(ws, out);
}

// Round 11
// 271.906 us; speedup vs baseline: 1.6620x; 1.4028x over previous
//
#include <hip/hip_runtime.h>
#include <hip/hip_bf16.h>
#include <math.h>

#define B 1024
#define D 512
#define KC 100000
#define MARGIN 0.3f
#define EPSSM 0.1f
#define NCP 782          // ceil(KC/128) column panels
#define NCP_PAD 784
#define NWREG (NCP_PAD * 8)   // wp regions of 16KB

typedef __attribute__((ext_vector_type(8))) short bf16x8;
typedef __attribute__((ext_vector_type(4))) float f32x4;

__device__ __forceinline__ unsigned cvtpk(float lo, float hi) {
    union { __hip_bfloat162 h2; unsigned u; } cv;
    cv.h2 = __float22bfloat162_rn(make_float2(lo, hi));
    return cv.u;
}

__device__ __forceinline__ void async16(const void* g, void* l) {
    __builtin_amdgcn_global_load_lds((const __attribute__((address_space(1))) unsigned int*)g,
                                     (__attribute__((address_space(3))) unsigned int*)l,
                                     16, 0, 0);
}

#define VMCNT(n) asm volatile("s_waitcnt vmcnt(" #n ")" ::: "memory")
#define FENCE    asm volatile("" ::: "memory")

// ws float layout: [0,B) sumexp | [B,2B) lin | [2B,3B) apbits | [3B,4B) anbits
// xp at +16KB (1MB, 64 regions x 16KB); wp after (6272 regions x 16KB = 100.4MB)

__global__ void init_ws(float* ws) {
    int i = blockIdx.x * blockDim.x + threadIdx.x;
    if (i < 2 * B) ws[i] = 0.f;
    else if (i < 3 * B) ((int*)ws)[i] = 0;
    else if (i < 4 * B) ((int*)ws)[i] = 0x7F800000;
}

// ===== PREP: triplet[0,256) + tlabel[256,512) + pack_x[512,768) + pack_w[768,768+25088) =====
__global__ __launch_bounds__(256) void prep_kernel(const float* __restrict__ x,
                                                   const float* __restrict__ W,
                                                   const float* __restrict__ bias,
                                                   const int* __restrict__ labels,
                                                   float* __restrict__ ws,
                                                   unsigned short* __restrict__ xp,
                                                   unsigned short* __restrict__ wp) {
    const int bid = blockIdx.x;
    const int tid = threadIdx.x;
    __shared__ float xs[8][D];
    __shared__ int labs[8];
    __shared__ float sqi[8];
    __shared__ float red_ap[8][4], red_an[8][4];

    if (bid >= 768) {
        // pack_w: region = cp*8+kt (16KB = [128 rows][8 units], unit pos = ku^(rloc&7))
        size_t oid = (size_t)(bid - 768) * 256 + tid;    // 6272 regions * 1024 units
        int region = (int)(oid >> 10);
        int p = (int)(oid & 1023);
        int rloc = p >> 3;
        int ku = (p & 7) ^ (rloc & 7);
        int cp = region >> 3, kt = region & 7;
        int c = cp * 128 + rloc;
        unsigned pv[4];
        if (c < KC) {
            const float* src = W + (size_t)c * D + kt * 64 + ku * 8;
            f32x4 a = __builtin_nontemporal_load((const f32x4*)src);
            f32x4 b2 = __builtin_nontemporal_load((const f32x4*)(src + 4));
            pv[0] = cvtpk(a[0], a[1]);  pv[1] = cvtpk(a[2], a[3]);
            pv[2] = cvtpk(b2[0], b2[1]); pv[3] = cvtpk(b2[2], b2[3]);
        } else {
            pv[0] = pv[1] = pv[2] = pv[3] = 0u;
        }
        *(uint4*)(wp + ((size_t)region << 13) + (size_t)p * 8) = *(uint4*)pv;
        return;
    }
    if (bid >= 512) {
        // pack_x: region = mblk*8+kt, same inner layout as wp
        int gid = (bid - 512) * 256 + tid;   // 1024 rows * 64
        int row = gid >> 6;
        int rest = gid & 63;
        int kt = rest >> 3, ku = rest & 7;
        const float* src = x + (size_t)row * D + kt * 64 + ku * 8;
        f32x4 a = *(const f32x4*)src;
        f32x4 b2 = *(const f32x4*)(src + 4);
        unsigned pv[4] = { cvtpk(a[0], a[1]), cvtpk(a[2], a[3]), cvtpk(b2[0], b2[1]), cvtpk(b2[2], b2[3]) };
        size_t off = ((size_t)((row >> 7) * 8 + kt) << 13) + (size_t)((row & 127) * 8 + (ku ^ (row & 7))) * 8;
        *(uint4*)(xp + off) = *(uint4*)pv;
        return;
    }
    if (bid >= 256) {
        // tlabel -> lin += 0.9*(x.Wlab + blab)
        int wid = tid >> 6, lane = tid & 63;
        int row = (bid - 256) * 4 + wid;
        int lab = labels[row];
        const float* xr = x + (size_t)row * D;
        const float* wr = W + (size_t)lab * D;
        float dsum = 0.f;
#pragma unroll
        for (int u = 0; u < 2; ++u) {
            int k = (lane * 2 + u) * 4;
            float4 a = *(const float4*)&xr[k];
            float4 w = *(const float4*)&wr[k];
            dsum += a.x * w.x + a.y * w.y + a.z * w.z + a.w * w.w;
        }
        for (int o = 32; o >= 1; o >>= 1) dsum += __shfl_xor(dsum, o);
        if (lane == 0) atomicAdd(&ws[B + row], (1.f - EPSSM) * (dsum + bias[lab]));
        return;
    }

    // triplet: batch-hard over a 512-j half, atomic bitwise max/min merge
    const int row0 = (bid >> 1) * 8;
    const int jbase = (bid & 1) * 512;
    for (int f = tid; f < 8 * (D / 4); f += 256) {
        int r = f / (D / 4);
        int p = f % (D / 4);
        *(float4*)&xs[r][p * 4] = *(const float4*)&x[(size_t)(row0 + r) * D + p * 4];
    }
    if (tid < 8) labs[tid] = labels[row0 + tid];
    __syncthreads();
    if (tid < 8) {
        float s = 0.f;
        for (int k = 0; k < D; ++k) s += xs[tid][k] * xs[tid][k];
        sqi[tid] = s;
    }
    __syncthreads();

    float ap[8], an[8];
#pragma unroll
    for (int r = 0; r < 8; ++r) { ap[r] = -INFINITY; an[r] = INFINITY; }

    for (int j = jbase + tid; j < jbase + 512; j += 256) {
        int labj = labels[j];
        float dot[8];
        float sqj = 0.f;
#pragma unroll
        for (int r = 0; r < 8; ++r) dot[r] = 0.f;
        for (int kc = 0; kc < D; kc += 32) {
            float4 xj[8];
#pragma unroll
            for (int u = 0; u < 8; ++u) xj[u] = *(const float4*)&x[(size_t)j * D + kc + u * 4];
#pragma unroll
            for (int u = 0; u < 8; ++u)
                sqj += xj[u].x * xj[u].x + xj[u].y * xj[u].y + xj[u].z * xj[u].z + xj[u].w * xj[u].w;
#pragma unroll
            for (int r = 0; r < 8; ++r) {
                float d = 0.f;
#pragma unroll
                for (int u = 0; u < 8; ++u) {
                    const float4 a = *(const float4*)&xs[r][kc + u * 4];
                    d += a.x * xj[u].x + a.y * xj[u].y + a.z * xj[u].z + a.w * xj[u].w;
                }
                dot[r] += d;
            }
        }
#pragma unroll
        for (int r = 0; r < 8; ++r) {
            float d2 = sqi[r] + sqj - 2.f * dot[r];
            float dist = sqrtf(fmaxf(d2, 1e-12f));
            if (labj == labs[r]) ap[r] = fmaxf(ap[r], dist);
            else an[r] = fminf(an[r], dist);
        }
    }
#pragma unroll
    for (int r = 0; r < 8; ++r) {
        for (int o = 32; o >= 1; o >>= 1) {
            ap[r] = fmaxf(ap[r], __shfl_xor(ap[r], o));
            an[r] = fminf(an[r], __shfl_xor(an[r], o));
        }
    }
    int wid = tid >> 6;
    if ((tid & 63) == 0) {
#pragma unroll
        for (int r = 0; r < 8; ++r) { red_ap[r][wid] = ap[r]; red_an[r][wid] = an[r]; }
    }
    __syncthreads();
    if (tid < 8) {
        float a = -INFINITY, n = INFINITY;
#pragma unroll
        for (int w = 0; w < 4; ++w) { a = fmaxf(a, red_ap[tid][w]); n = fminf(n, red_an[tid][w]); }
        a = fmaxf(a, 0.f);
        int* apbits = (int*)(ws + 2 * B);
        int* anbits = (int*)(ws + 3 * B);
        atomicMax(&apbits[row0 + tid], __float_as_int(a));
        atomicMin(&anbits[row0 + tid], __float_as_int(n));
    }
}

// ============ 128x128xBK64 bf16 MFMA GEMM: 2 blocks/CU, depth-2, conflict-free ============
// 256 thr (4 waves 2Mx2N, wave tile 64x64). LDS 64KB static = 2 parities x (A 16KB + B 16KB)
// -> 2 blocks/CU: barrier stalls of one block overlap the other's compute (TLP).
// Depth-2 K-tile prefetch, uniform VMCNT(8); stage into consumed parity AFTER barrier2.
// Baked-swizzle pack (R6-verified formulas) -> ds_read_b128 frags conflict-free.
// XCD-grouped mapping (R3-verified): 8 row-blocks of one column-panel on one XCD.
__global__ __launch_bounds__(256, 2) void ce_gemm_k(const unsigned short* __restrict__ xp,
                                                    const unsigned short* __restrict__ wp,
                                                    const float* __restrict__ bias,
                                                    float* __restrict__ ws) {
    const int b = blockIdx.x;
    const int xcd = b & 7, slot = b >> 3;
    const int cp = (slot >> 3) * 8 + xcd;   // column panel (128 cols)
    const int mb = slot & 7;                // row block (128 rows)
    if (cp >= NCP) return;
    const int rowbase = mb * 128;
    const int cbase = cp * 128;

    __shared__ unsigned short lds[32768];   // 64 KB: par*16384 + {A:0, B:8192}

    const int tid = threadIdx.x;
    const int lane = tid & 63;
    const int wid = tid >> 6;
    const int wm = wid >> 1, wn = wid & 1;  // 2M x 2N, wave tile 64x64
    const int q = lane >> 4, l15 = lane & 15;

    f32x4 acc[4][4];
#pragma unroll
    for (int m = 0; m < 4; ++m)
#pragma unroll
        for (int n = 0; n < 4; ++n) acc[m][n] = (f32x4){0.f, 0.f, 0.f, 0.f};

#define STAGE(kt_) {                                                               \
        unsigned short* lA = &lds[((kt_) & 1) * 16384];                            \
        unsigned short* lB = lA + 8192;                                            \
        const unsigned short* ga = xp + ((size_t)(mb * 8 + (kt_)) << 13);          \
        const unsigned short* gb = wp + ((size_t)(cp * 8 + (kt_)) << 13);          \
        _Pragma("unroll")                                                          \
        for (int i = 0; i < 4; ++i) {                                              \
            async16(ga + (i * 256 + tid) * 8, lA + (i * 256 + tid) * 8);           \
            async16(gb + (i * 256 + tid) * 8, lB + (i * 256 + tid) * 8);           \
        } }
#define READS(ks_, par_) {                                                         \
        const unsigned short* sA = &lds[(par_) * 16384];                           \
        const unsigned short* sB = sA + 8192;                                      \
        _Pragma("unroll") for (int m = 0; m < 4; ++m) {                            \
            int rl = wm * 64 + m * 16 + l15;                                       \
            af[m] = *(const bf16x8*)&sA[(rl * 8 + (((ks_) * 4 + q) ^ (rl & 7))) * 8]; } \
        _Pragma("unroll") for (int n = 0; n < 4; ++n) {                            \
            int rl = wn * 64 + n * 16 + l15;                                       \
            bfr[n] = *(const bf16x8*)&sB[(rl * 8 + (((ks_) * 4 + q) ^ (rl & 7))) * 8]; } }
#define MFMAC() {                                                                  \
        __builtin_amdgcn_s_setprio(1);                                             \
        _Pragma("unroll") for (int m = 0; m < 4; ++m)                              \
        _Pragma("unroll") for (int n = 0; n < 4; ++n)                              \
            acc[m][n] = __builtin_amdgcn_mfma_f32_16x16x32_bf16(                   \
                af[m], bfr[n], acc[m][n], 0, 0, 0);                                \
        __builtin_amdgcn_s_setprio(0); }

    STAGE(0); STAGE(1);   // 16 ops in flight

    bf16x8 af[4], bfr[4];
#pragma unroll
    for (int kt = 0; kt < 8; ++kt) {
        const int par = kt & 1;
        if (kt < 7) { VMCNT(8); } else { VMCNT(0); }
        __builtin_amdgcn_s_barrier(); FENCE;
        READS(0, par);
        MFMAC();
        READS(1, par);
        MFMAC();
        __builtin_amdgcn_s_barrier(); FENCE;
        if (kt + 2 < 8) STAGE(kt + 2);   // into parity just consumed (reads done)
    }
#undef STAGE
#undef READS
#undef MFMAC

    // ---- epilogue: per-row sum(exp)/sum(logit); shfl over l15; [128][2] LDS; atomics ----
    __syncthreads();
    float* redE = (float*)lds;           // [128][2]
    float* redL = redE + 256;            // [128][2]
    float biasv[4];
#pragma unroll
    for (int n = 0; n < 4; ++n) {
        int cc = cbase + wn * 64 + n * 16 + l15;
        biasv[n] = bias[cc < KC ? cc : KC - 1];
    }
#pragma unroll
    for (int m = 0; m < 4; ++m) {
#pragma unroll
        for (int r2 = 0; r2 < 4; ++r2) {
            float pe = 0.f, pl = 0.f;
#pragma unroll
            for (int n = 0; n < 4; ++n) {
                int cc = cbase + wn * 64 + n * 16 + l15;
                if (cc < KC) {
                    float lg = acc[m][n][r2] + biasv[n];
                    pe += __expf(lg);
                    pl += lg;
                }
            }
#pragma unroll
            for (int o = 1; o < 16; o <<= 1) {
                pe += __shfl_xor(pe, o);
                pl += __shfl_xor(pl, o);
            }
            if (l15 == 0) {
                int rowl = wm * 64 + m * 16 + q * 4 + r2;
                redE[rowl * 2 + wn] = pe;
                redL[rowl * 2 + wn] = pl;
            }
        }
    }
    __syncthreads();
    if (tid < 128) {
        float se = redE[tid * 2] + redE[tid * 2 + 1];
        float sl = redL[tid * 2] + redL[tid * 2 + 1];
        atomicAdd(&ws[rowbase + tid], se);
        atomicAdd(&ws[B + rowbase + tid], (EPSSM / (float)KC) * sl);
    }
}

// ---------------- final combine ----------------
__global__ __launch_bounds__(1024) void final_kernel(const float* __restrict__ ws,
                                                     float* __restrict__ out) {
    const float* sumexp = ws;
    const float* lin = ws + B;
    const int* apbits = (const int*)(ws + 2 * B);
    const int* anbits = (const int*)(ws + 3 * B);
    int i = threadIdx.x;
    float ce = logf(sumexp[i]) - lin[i];
    float ap = __int_as_float(apbits[i]);
    float an = __int_as_float(anbits[i]);
    float v = ce + fmaxf(ap - an + MARGIN, 0.f);
    for (int o = 32; o >= 1; o >>= 1) v += __shfl_xor(v, o);
    __shared__ float red[16];
    int wid = threadIdx.x >> 6, lane = threadIdx.x & 63;
    if (lane == 0) red[wid] = v;
    __syncthreads();
    if (threadIdx.x == 0) {
        float s = 0.f;
#pragma unroll
        for (int w = 0; w < 16; ++w) s += red[w];
        out[0] = s / (float)B;
    }
}

extern "C" void kernel_launch(void* const* d_in, const int* in_sizes, int n_in,
                              void* d_out, int out_size, void* d_ws, size_t ws_size,
                              hipStream_t stream) {
    const float* x = (const float*)d_in[0];
    const float* W = (const float*)d_in[1];
    const float* bias = (const float*)d_in[2];
    const int* labels = (const int*)d_in[3];
    float* out = (float*)d_out;
    float* ws = (float*)d_ws;

    unsigned short* xp = (unsigned short*)((char*)d_ws + 16384);
    unsigned short* wp = xp + (size_t)B * D;   // 6272 regions x 8192 ushorts

    init_ws<<<16, 256, 0, stream>>>(ws);
    prep_kernel<<<768 + NWREG * 4, 256, 0, stream>>>(x, W, bias, labels, ws, xp, wp);
    ce_gemm_k<<<8 * NCP_PAD, 256, 0, stream>>>(xp, wp, bias, ws);
    final_kernel<<<1, 1024, 0, stream>>>(ws, out);
}

// Round 12
// 265.425 us; speedup vs baseline: 1.7026x; 1.0244x over previous
//
#include <hip/hip_runtime.h>
#include <hip/hip_bf16.h>
#include <math.h>

#define B 1024
#define D 512
#define KC 100000
#define MARGIN 0.3f
#define EPSSM 0.1f
#define NCP 782          // ceil(KC/128) column panels
#define NCP_PAD 784

typedef __attribute__((ext_vector_type(8))) short bf16x8;
typedef __attribute__((ext_vector_type(4))) float f32x4;

__device__ __forceinline__ unsigned cvtpk(float lo, float hi) {
    union { __hip_bfloat162 h2; unsigned u; } cv;
    cv.h2 = __float22bfloat162_rn(make_float2(lo, hi));
    return cv.u;
}

__device__ __forceinline__ void async16(const void* g, void* l) {
    __builtin_amdgcn_global_load_lds((const __attribute__((address_space(1))) unsigned int*)g,
                                     (__attribute__((address_space(3))) unsigned int*)l,
                                     16, 0, 0);
}

#define VMCNT(n) asm volatile("s_waitcnt vmcnt(" #n ")" ::: "memory")
#define FENCE    asm volatile("" ::: "memory")

// ws float layout: [0,B) sumexp | [B,2B) lin | [2B,3B) apbits | [3B,4B) anbits
// xp (packed bf16 x) at byte 16384: 128 regions x 8KB = 1MB.

__global__ void init_ws(float* ws) {
    int i = blockIdx.x * blockDim.x + threadIdx.x;
    if (i < 2 * B) ws[i] = 0.f;
    else if (i < 3 * B) ((int*)ws)[i] = 0;
    else if (i < 4 * B) ((int*)ws)[i] = 0x7F800000;
}

// ===== PREP: triplet[0,256) + tlabel[256,512) + pack_x[512,768) =====
__global__ __launch_bounds__(256) void prep_kernel(const float* __restrict__ x,
                                                   const float* __restrict__ W,
                                                   const float* __restrict__ bias,
                                                   const int* __restrict__ labels,
                                                   float* __restrict__ ws,
                                                   unsigned short* __restrict__ xp) {
    const int bid = blockIdx.x;
    const int tid = threadIdx.x;
    __shared__ float xs[8][D];
    __shared__ int labs[8];
    __shared__ float sqi[8];
    __shared__ float red_ap[8][4], red_an[8][4];

    if (bid >= 512) {
        // pack_x: region (mb*16+kt) = 8KB = [128 rows][4 units of 8 bf16],
        // unit pos qpos holds k-chunk ku = qpos ^ ((row>>1)&3)  (baked swizzle)
        int gid = (bid - 512) * 256 + tid;       // 128 regions * 512 units = 65536
        int region = gid >> 9;
        int u = gid & 511;
        int rloc = u >> 2, qpos = u & 3;
        int ku = qpos ^ ((rloc >> 1) & 3);
        int mb = region >> 4, kt = region & 15;
        const float* src = x + (size_t)(mb * 128 + rloc) * D + kt * 32 + ku * 8;
        f32x4 a = *(const f32x4*)src;
        f32x4 b2 = *(const f32x4*)(src + 4);
        unsigned pv[4] = { cvtpk(a[0], a[1]), cvtpk(a[2], a[3]), cvtpk(b2[0], b2[1]), cvtpk(b2[2], b2[3]) };
        *(uint4*)(xp + (size_t)region * 4096 + (size_t)u * 8) = *(uint4*)pv;
        return;
    }
    if (bid >= 256) {
        // tlabel -> lin += 0.9*(x.Wlab + blab)
        int wid = tid >> 6, lane = tid & 63;
        int row = (bid - 256) * 4 + wid;
        int lab = labels[row];
        const float* xr = x + (size_t)row * D;
        const float* wr = W + (size_t)lab * D;
        float dsum = 0.f;
#pragma unroll
        for (int u = 0; u < 2; ++u) {
            int k = (lane * 2 + u) * 4;
            float4 a = *(const float4*)&xr[k];
            float4 w = *(const float4*)&wr[k];
            dsum += a.x * w.x + a.y * w.y + a.z * w.z + a.w * w.w;
        }
        for (int o = 32; o >= 1; o >>= 1) dsum += __shfl_xor(dsum, o);
        if (lane == 0) atomicAdd(&ws[B + row], (1.f - EPSSM) * (dsum + bias[lab]));
        return;
    }

    // triplet: batch-hard over a 512-j half, atomic bitwise max/min merge
    const int row0 = (bid >> 1) * 8;
    const int jbase = (bid & 1) * 512;
    for (int f = tid; f < 8 * (D / 4); f += 256) {
        int r = f / (D / 4);
        int p = f % (D / 4);
        *(float4*)&xs[r][p * 4] = *(const float4*)&x[(size_t)(row0 + r) * D + p * 4];
    }
    if (tid < 8) labs[tid] = labels[row0 + tid];
    __syncthreads();
    if (tid < 8) {
        float s = 0.f;
        for (int k = 0; k < D; ++k) s += xs[tid][k] * xs[tid][k];
        sqi[tid] = s;
    }
    __syncthreads();

    float ap[8], an[8];
#pragma unroll
    for (int r = 0; r < 8; ++r) { ap[r] = -INFINITY; an[r] = INFINITY; }

    for (int j = jbase + tid; j < jbase + 512; j += 256) {
        int labj = labels[j];
        float dot[8];
        float sqj = 0.f;
#pragma unroll
        for (int r = 0; r < 8; ++r) dot[r] = 0.f;
        for (int kc = 0; kc < D; kc += 32) {
            float4 xj[8];
#pragma unroll
            for (int u = 0; u < 8; ++u) xj[u] = *(const float4*)&x[(size_t)j * D + kc + u * 4];
#pragma unroll
            for (int u = 0; u < 8; ++u)
                sqj += xj[u].x * xj[u].x + xj[u].y * xj[u].y + xj[u].z * xj[u].z + xj[u].w * xj[u].w;
#pragma unroll
            for (int r = 0; r < 8; ++r) {
                float d = 0.f;
#pragma unroll
                for (int u = 0; u < 8; ++u) {
                    const float4 a = *(const float4*)&xs[r][kc + u * 4];
                    d += a.x * xj[u].x + a.y * xj[u].y + a.z * xj[u].z + a.w * xj[u].w;
                }
                dot[r] += d;
            }
        }
#pragma unroll
        for (int r = 0; r < 8; ++r) {
            float d2 = sqi[r] + sqj - 2.f * dot[r];
            float dist = sqrtf(fmaxf(d2, 1e-12f));
            if (labj == labs[r]) ap[r] = fmaxf(ap[r], dist);
            else an[r] = fminf(an[r], dist);
        }
    }
#pragma unroll
    for (int r = 0; r < 8; ++r) {
        for (int o = 32; o >= 1; o >>= 1) {
            ap[r] = fmaxf(ap[r], __shfl_xor(ap[r], o));
            an[r] = fminf(an[r], __shfl_xor(an[r], o));
        }
    }
    int wid = tid >> 6;
    if ((tid & 63) == 0) {
#pragma unroll
        for (int r = 0; r < 8; ++r) { red_ap[r][wid] = ap[r]; red_an[r][wid] = an[r]; }
    }
    __syncthreads();
    if (tid < 8) {
        float a = -INFINITY, n = INFINITY;
#pragma unroll
        for (int w = 0; w < 4; ++w) { a = fmaxf(a, red_ap[tid][w]); n = fminf(n, red_an[tid][w]); }
        a = fmaxf(a, 0.f);
        int* apbits = (int*)(ws + 2 * B);
        int* anbits = (int*)(ws + 3 * B);
        atomicMax(&apbits[row0 + tid], __float_as_int(a));
        atomicMin(&anbits[row0 + tid], __float_as_int(n));
    }
}

// ========= 128x128xBK32 GEMM: A bf16-packed, B fp32 direct from W, 3 blocks/CU =========
// 256 thr (4 waves 2Mx2N, wave tile 64x64). Parity = A 8KB (bf16, baked swizzle) +
// B 16KB (fp32, XOR'd per-lane SOURCE, linear dest) = 24KB; x2 = 48KB -> 3 blocks/CU.
// Depth-2 K-tile prefetch, 6 gload_lds/thread/tile -> uniform VMCNT(6); stage into the
// just-consumed parity AFTER barrier2 (R11-proven order). B frags cvt to bf16 in-reg.
// No pack_w: W fp32 read straight from HBM/L2 (XCD-grouped: 8 row-blocks share panel).
__global__ __launch_bounds__(256, 3) void ce_gemm_d(const unsigned short* __restrict__ xp,
                                                    const float* __restrict__ W,
                                                    const float* __restrict__ bias,
                                                    float* __restrict__ ws) {
    const int b = blockIdx.x;
    const int xcd = b & 7, slot = b >> 3;
    const int cp = (slot >> 3) * 8 + xcd;   // column panel (128 cols)
    const int mb = slot & 7;                // row block (128 rows)
    if (cp >= NCP) return;
    const int rowbase = mb * 128;
    const int cbase = cp * 128;

    __shared__ unsigned short lds[24576];   // 48KB: parity p at p*12288 {A:4096 ush, B:8192 ush}

    const int tid = threadIdx.x;
    const int lane = tid & 63;
    const int wid = tid >> 6;
    const int wm = wid >> 1, wn = wid & 1;  // 2M x 2N, wave tile 64x64
    const int q = lane >> 4, l15 = lane & 15;

    f32x4 acc[4][4];
#pragma unroll
    for (int m = 0; m < 4; ++m)
#pragma unroll
        for (int n = 0; n < 4; ++n) acc[m][n] = (f32x4){0.f, 0.f, 0.f, 0.f};

    // B source guard: clamp row to KC-1 (epilogue's cc<KC drops those columns)
#define STAGE(kt_) {                                                               \
        unsigned short* lA = &lds[((kt_) & 1) * 12288];                            \
        float* lB = (float*)&lds[((kt_) & 1) * 12288 + 4096];                      \
        const unsigned short* ga = xp + (size_t)(mb * 16 + (kt_)) * 4096;          \
        async16(ga + tid * 8, lA + tid * 8);                                       \
        async16(ga + 2048 + tid * 8, lA + 2048 + tid * 8);                         \
        _Pragma("unroll")                                                          \
        for (int i = 0; i < 4; ++i) {                                              \
            int u = i * 256 + tid;                                                 \
            int row = u >> 3;                                                      \
            int lu = (u & 7) ^ (row & 7);                                          \
            int rc = cbase + row; rc = rc < KC ? rc : KC - 1;                      \
            async16(&W[(size_t)rc * D + (kt_) * 32 + lu * 4], lB + u * 4);         \
        } }
#define READS(par_) {                                                              \
        const unsigned short* sA = &lds[(par_) * 12288];                           \
        const float* sB = (const float*)&lds[(par_) * 12288 + 4096];               \
        _Pragma("unroll") for (int m = 0; m < 4; ++m) {                            \
            int rl = wm * 64 + m * 16 + l15;                                       \
            af[m] = *(const bf16x8*)&sA[(rl * 4 + (q ^ ((rl >> 1) & 3))) * 8]; }   \
        _Pragma("unroll") for (int n = 0; n < 4; ++n) {                            \
            int rl = wn * 64 + n * 16 + l15;                                       \
            f32x4 b0 = *(const f32x4*)&sB[rl * 32 + ((q * 2) ^ (rl & 7)) * 4];     \
            f32x4 b1 = *(const f32x4*)&sB[rl * 32 + ((q * 2 + 1) ^ (rl & 7)) * 4]; \
            union { unsigned u[4]; bf16x8 v; } cv;                                 \
            cv.u[0] = cvtpk(b0[0], b0[1]); cv.u[1] = cvtpk(b0[2], b0[3]);          \
            cv.u[2] = cvtpk(b1[0], b1[1]); cv.u[3] = cvtpk(b1[2], b1[3]);          \
            bfr[n] = cv.v; } }
#define MFMAC() {                                                                  \
        __builtin_amdgcn_s_setprio(1);                                             \
        _Pragma("unroll") for (int m = 0; m < 4; ++m)                              \
        _Pragma("unroll") for (int n = 0; n < 4; ++n)                              \
            acc[m][n] = __builtin_amdgcn_mfma_f32_16x16x32_bf16(                   \
                af[m], bfr[n], acc[m][n], 0, 0, 0);                                \
        __builtin_amdgcn_s_setprio(0); }

    STAGE(0); STAGE(1);   // 12 ops/thread in flight

    bf16x8 af[4], bfr[4];
#pragma unroll
    for (int kt = 0; kt < 16; ++kt) {
        const int par = kt & 1;
        if (kt < 15) { VMCNT(6); } else { VMCNT(0); }
        __builtin_amdgcn_s_barrier(); FENCE;
        READS(par);
        MFMAC();
        __builtin_amdgcn_s_barrier(); FENCE;
        if (kt + 2 < 16) STAGE(kt + 2);   // into parity just consumed (reads done)
    }
#undef STAGE
#undef READS
#undef MFMAC

    // ---- epilogue: per-row sum(exp)/sum(logit); shfl over l15; [128][2] LDS; atomics ----
    __syncthreads();
    float* redE = (float*)lds;           // [128][2]
    float* redL = redE + 256;            // [128][2]
    float biasv[4];
#pragma unroll
    for (int n = 0; n < 4; ++n) {
        int cc = cbase + wn * 64 + n * 16 + l15;
        biasv[n] = bias[cc < KC ? cc : KC - 1];
    }
#pragma unroll
    for (int m = 0; m < 4; ++m) {
#pragma unroll
        for (int r2 = 0; r2 < 4; ++r2) {
            float pe = 0.f, pl = 0.f;
#pragma unroll
            for (int n = 0; n < 4; ++n) {
                int cc = cbase + wn * 64 + n * 16 + l15;
                if (cc < KC) {
                    float lg = acc[m][n][r2] + biasv[n];
                    pe += __expf(lg);
                    pl += lg;
                }
            }
#pragma unroll
            for (int o = 1; o < 16; o <<= 1) {
                pe += __shfl_xor(pe, o);
                pl += __shfl_xor(pl, o);
            }
            if (l15 == 0) {
                int rowl = wm * 64 + m * 16 + q * 4 + r2;
                redE[rowl * 2 + wn] = pe;
                redL[rowl * 2 + wn] = pl;
            }
        }
    }
    __syncthreads();
    if (tid < 128) {
        float se = redE[tid * 2] + redE[tid * 2 + 1];
        float sl = redL[tid * 2] + redL[tid * 2 + 1];
        atomicAdd(&ws[rowbase + tid], se);
        atomicAdd(&ws[B + rowbase + tid], (EPSSM / (float)KC) * sl);
    }
}

// ---------------- final combine ----------------
__global__ __launch_bounds__(1024) void final_kernel(const float* __restrict__ ws,
                                                     float* __restrict__ out) {
    const float* sumexp = ws;
    const float* lin = ws + B;
    const int* apbits = (const int*)(ws + 2 * B);
    const int* anbits = (const int*)(ws + 3 * B);
    int i = threadIdx.x;
    float ce = logf(sumexp[i]) - lin[i];
    float ap = __int_as_float(apbits[i]);
    float an = __int_as_float(anbits[i]);
    float v = ce + fmaxf(ap - an + MARGIN, 0.f);
    for (int o = 32; o >= 1; o >>= 1) v += __shfl_xor(v, o);
    __shared__ float red[16];
    int wid = threadIdx.x >> 6, lane = threadIdx.x & 63;
    if (lane == 0) red[wid] = v;
    __syncthreads();
    if (threadIdx.x == 0) {
        float s = 0.f;
#pragma unroll
        for (int w = 0; w < 16; ++w) s += red[w];
        out[0] = s / (float)B;
    }
}

extern "C" void kernel_launch(void* const* d_in, const int* in_sizes, int n_in,
                              void* d_out, int out_size, void* d_ws, size_t ws_size,
                              hipStream_t stream) {
    const float* x = (const float*)d_in[0];
    const float* W = (const float*)d_in[1];
    const float* bias = (const float*)d_in[2];
    const int* labels = (const int*)d_in[3];
    float* out = (float*)d_out;
    float* ws = (float*)d_ws;

    unsigned short* xp = (unsigned short*)((char*)d_ws + 16384);   // 1MB packed x

    init_ws<<<16, 256, 0, stream>>>(ws);
    prep_kernel<<<768, 256, 0, stream>>>(x, W, bias, labels, ws, xp);
    ce_gemm_d<<<8 * NCP_PAD, 256, 0, stream>>>(xp, W, bias, ws);
    final_kernel<<<1, 1024, 0, stream>>>(ws, out);
}

// Round 13
// 219.215 us; speedup vs baseline: 2.0615x; 1.2108x over previous
//
#include <hip/hip_runtime.h>
#include <hip/hip_bf16.h>
#include <math.h>

#define B 1024
#define D 512
#define KC 100000
#define MARGIN 0.3f
#define EPSSM 0.1f
#define NCP 782          // ceil(KC/128) column panels
#define NCP_PAD 784

typedef __attribute__((ext_vector_type(8))) short bf16x8;
typedef __attribute__((ext_vector_type(4))) float f32x4;

__device__ __forceinline__ unsigned cvtpk(float lo, float hi) {
    union { __hip_bfloat162 h2; unsigned u; } cv;
    cv.h2 = __float22bfloat162_rn(make_float2(lo, hi));
    return cv.u;
}

__device__ __forceinline__ void async16(const void* g, void* l) {
    __builtin_amdgcn_global_load_lds((const __attribute__((address_space(1))) unsigned int*)g,
                                     (__attribute__((address_space(3))) unsigned int*)l,
                                     16, 0, 0);
}

#define VMCNT(n) asm volatile("s_waitcnt vmcnt(" #n ")" ::: "memory")
#define LGKM0    asm volatile("s_waitcnt lgkmcnt(0)" ::: "memory")
#define FENCE    asm volatile("" ::: "memory")

// ws float layout: [0,B) sumexp | [B,2B) lin | [2B,3B) apbits | [3B,4B) anbits
// xp (packed bf16 x) at byte 16384: 64 regions x 16KB = 1MB.

__global__ void init_ws(float* ws) {
    int i = blockIdx.x * blockDim.x + threadIdx.x;
    if (i < 2 * B) ws[i] = 0.f;
    else if (i < 3 * B) ((int*)ws)[i] = 0;
    else if (i < 4 * B) ((int*)ws)[i] = 0x7F800000;
}

// ===== PREP: triplet[0,256) + tlabel[256,512) + pack_x[512,768) =====
__global__ __launch_bounds__(256) void prep_kernel(const float* __restrict__ x,
                                                   const float* __restrict__ W,
                                                   const float* __restrict__ bias,
                                                   const int* __restrict__ labels,
                                                   float* __restrict__ ws,
                                                   unsigned short* __restrict__ xp) {
    const int bid = blockIdx.x;
    const int tid = threadIdx.x;
    __shared__ float xs[8][D];
    __shared__ int labs[8];
    __shared__ float sqi[8];
    __shared__ float red_ap[8][4], red_an[8][4];

    if (bid >= 512) {
        // pack_x: region (mb*16+kt) = 16KB = [256 rows][4 units of 8 bf16],
        // data unit ku stored at pos qpos = ku ^ ((rloc>>1)&3)  (baked swizzle)
        int gid = (bid - 512) * 256 + tid;       // 64 regions * 1024 units
        int region = gid >> 10;
        int p = gid & 1023;
        int rloc = p >> 2, qpos = p & 3;
        int ku = qpos ^ ((rloc >> 1) & 3);
        int mb = region >> 4, kt = region & 15;
        const float* src = x + (size_t)(mb * 256 + rloc) * D + kt * 32 + ku * 8;
        f32x4 a = *(const f32x4*)src;
        f32x4 b2 = *(const f32x4*)(src + 4);
        unsigned pv[4] = { cvtpk(a[0], a[1]), cvtpk(a[2], a[3]), cvtpk(b2[0], b2[1]), cvtpk(b2[2], b2[3]) };
        *(uint4*)(xp + (size_t)region * 8192 + (size_t)p * 8) = *(uint4*)pv;
        return;
    }
    if (bid >= 256) {
        // tlabel -> lin += 0.9*(x.Wlab + blab)
        int wid = tid >> 6, lane = tid & 63;
        int row = (bid - 256) * 4 + wid;
        int lab = labels[row];
        const float* xr = x + (size_t)row * D;
        const float* wr = W + (size_t)lab * D;
        float dsum = 0.f;
#pragma unroll
        for (int u = 0; u < 2; ++u) {
            int k = (lane * 2 + u) * 4;
            float4 a = *(const float4*)&xr[k];
            float4 w = *(const float4*)&wr[k];
            dsum += a.x * w.x + a.y * w.y + a.z * w.z + a.w * w.w;
        }
        for (int o = 32; o >= 1; o >>= 1) dsum += __shfl_xor(dsum, o);
        if (lane == 0) atomicAdd(&ws[B + row], (1.f - EPSSM) * (dsum + bias[lab]));
        return;
    }

    // triplet: batch-hard over a 512-j half, atomic bitwise max/min merge
    const int row0 = (bid >> 1) * 8;
    const int jbase = (bid & 1) * 512;
    for (int f = tid; f < 8 * (D / 4); f += 256) {
        int r = f / (D / 4);
        int p = f % (D / 4);
        *(float4*)&xs[r][p * 4] = *(const float4*)&x[(size_t)(row0 + r) * D + p * 4];
    }
    if (tid < 8) labs[tid] = labels[row0 + tid];
    __syncthreads();
    if (tid < 8) {
        float s = 0.f;
        for (int k = 0; k < D; ++k) s += xs[tid][k] * xs[tid][k];
        sqi[tid] = s;
    }
    __syncthreads();

    float ap[8], an[8];
#pragma unroll
    for (int r = 0; r < 8; ++r) { ap[r] = -INFINITY; an[r] = INFINITY; }

    for (int j = jbase + tid; j < jbase + 512; j += 256) {
        int labj = labels[j];
        float dot[8];
        float sqj = 0.f;
#pragma unroll
        for (int r = 0; r < 8; ++r) dot[r] = 0.f;
        for (int kc = 0; kc < D; kc += 32) {
            float4 xj[8];
#pragma unroll
            for (int u = 0; u < 8; ++u) xj[u] = *(const float4*)&x[(size_t)j * D + kc + u * 4];
#pragma unroll
            for (int u = 0; u < 8; ++u)
                sqj += xj[u].x * xj[u].x + xj[u].y * xj[u].y + xj[u].z * xj[u].z + xj[u].w * xj[u].w;
#pragma unroll
            for (int r = 0; r < 8; ++r) {
                float d = 0.f;
#pragma unroll
                for (int u = 0; u < 8; ++u) {
                    const float4 a = *(const float4*)&xs[r][kc + u * 4];
                    d += a.x * xj[u].x + a.y * xj[u].y + a.z * xj[u].z + a.w * xj[u].w;
                }
                dot[r] += d;
            }
        }
#pragma unroll
        for (int r = 0; r < 8; ++r) {
            float d2 = sqi[r] + sqj - 2.f * dot[r];
            float dist = sqrtf(fmaxf(d2, 1e-12f));
            if (labj == labs[r]) ap[r] = fmaxf(ap[r], dist);
            else an[r] = fminf(an[r], dist);
        }
    }
#pragma unroll
    for (int r = 0; r < 8; ++r) {
        for (int o = 32; o >= 1; o >>= 1) {
            ap[r] = fmaxf(ap[r], __shfl_xor(ap[r], o));
            an[r] = fminf(an[r], __shfl_xor(an[r], o));
        }
    }
    int wid = tid >> 6;
    if ((tid & 63) == 0) {
#pragma unroll
        for (int r = 0; r < 8; ++r) { red_ap[r][wid] = ap[r]; red_an[r][wid] = an[r]; }
    }
    __syncthreads();
    if (tid < 8) {
        float a = -INFINITY, n = INFINITY;
#pragma unroll
        for (int w = 0; w < 4; ++w) { a = fmaxf(a, red_ap[tid][w]); n = fminf(n, red_an[tid][w]); }
        a = fmaxf(a, 0.f);
        int* apbits = (int*)(ws + 2 * B);
        int* anbits = (int*)(ws + 3 * B);
        atomicMax(&apbits[row0 + tid], __float_as_int(a));
        atomicMin(&anbits[row0 + tid], __float_as_int(n));
    }
}

// ===== 256x128xBK32 GEMM: A gload_lds (3-slot, linear src), B reg-staged from fp32 W =====
// 256 thr, 4 waves (2Mx2N; wave tile 128x64; 32 MFMA vs 12 ds_read+2 ds_write per phase).
// A: 3 x 16KB LDS slots (writes land 2 barriers behind readers). B: coalesced dwordx4
// loads -> 3 reg-sets -> cvtpk -> swizzled ds_write_b128 into opposite B-parity (2x8KB).
// Ledger (issue order per phase: B(kt+3) then A(kt+2)): steady VMCNT(8); kt=14: 4; 15: 0.
// All LDS access patterns are the measured-conflict-free baked-swizzle family.
__global__ __launch_bounds__(256, 2) void ce_gemm_r(const unsigned short* __restrict__ xp,
                                                    const float* __restrict__ W,
                                                    const float* __restrict__ bias,
                                                    float* __restrict__ ws) {
    const int b = blockIdx.x;
    const int xcd = b & 7, slot = b >> 3;
    const int cp = (slot >> 2) * 8 + xcd;   // column panel (128 cols)
    const int mb = slot & 3;                // row block (256 rows)
    if (cp >= NCP) return;
    const int rowbase = mb * 256;
    const int cbase = cp * 128;

    __shared__ unsigned short lds[32768];   // 64KB: A slots s*8192 (s=0..2), B par 24576+p*4096

    const int tid = threadIdx.x;
    const int lane = tid & 63;
    const int wid = tid >> 6;
    const int wm = wid >> 1, wn = wid & 1;  // wave tile 128 rows x 64 cols
    const int q = lane >> 4, l15 = lane & 15;

    // B staging geometry: thread -> (col-class rB, 16-float half)
    const int rB = tid >> 1;
    const int ku0 = (tid & 1) * 2;
    const int swB = (rB >> 1) & 3;
    const int p0 = rB * 4 + (ku0 ^ swB);
    const int p1 = rB * 4 + ((ku0 + 1) ^ swB);
    int rc = cbase + rB; rc = rc < KC ? rc : KC - 1;
    const float* pW = W + (size_t)rc * D + (tid & 1) * 16;

    f32x4 acc[8][4];
#pragma unroll
    for (int m = 0; m < 8; ++m)
#pragma unroll
        for (int n = 0; n < 4; ++n) acc[m][n] = (f32x4){0.f, 0.f, 0.f, 0.f};

    f32x4 bsv[3][4];   // 3 reg-sets x 16 floats

#define BLOAD(s_, kt_) {                                                           \
        _Pragma("unroll") for (int j = 0; j < 4; ++j)                              \
            bsv[s_][j] = *(const f32x4*)(pW + (kt_) * 32 + j * 4);                 \
        FENCE; }
#define ALOAD(kt_) {                                                               \
        const unsigned short* ga = xp + (size_t)(mb * 16 + (kt_)) * 8192;          \
        unsigned short* lA = &lds[((kt_) % 3) * 8192];                             \
        _Pragma("unroll") for (int i = 0; i < 4; ++i)                              \
            async16(ga + (i * 256 + tid) * 8, lA + (i * 256 + tid) * 8);           \
        FENCE; }
#define BCVW(s_, kt_) {                                                            \
        unsigned short* lB = &lds[24576 + ((kt_) & 1) * 4096];                     \
        unsigned u0[4] = { cvtpk(bsv[s_][0][0], bsv[s_][0][1]),                    \
                           cvtpk(bsv[s_][0][2], bsv[s_][0][3]),                    \
                           cvtpk(bsv[s_][1][0], bsv[s_][1][1]),                    \
                           cvtpk(bsv[s_][1][2], bsv[s_][1][3]) };                  \
        unsigned u1[4] = { cvtpk(bsv[s_][2][0], bsv[s_][2][1]),                    \
                           cvtpk(bsv[s_][2][2], bsv[s_][2][3]),                    \
                           cvtpk(bsv[s_][3][0], bsv[s_][3][1]),                    \
                           cvtpk(bsv[s_][3][2], bsv[s_][3][3]) };                  \
        *(uint4*)&lB[p0 * 8] = *(uint4*)u0;                                        \
        *(uint4*)&lB[p1 * 8] = *(uint4*)u1; }

    // prologue (ledger history): B0; B1; A0; B2; A1
    BLOAD(0, 0); BLOAD(1, 1); ALOAD(0); BLOAD(2, 2); ALOAD(1);
    VMCNT(16);            // B0 regs complete
    BCVW(0, 0);           // B(0) into parity 0
    LGKM0;

    bf16x8 af[4], bfr[4];
#pragma unroll
    for (int kt = 0; kt < 16; ++kt) {
        if (kt <= 13) { VMCNT(8); } else if (kt == 14) { VMCNT(4); } else { VMCNT(0); }
        __builtin_amdgcn_s_barrier(); FENCE;

        const unsigned short* sA = &lds[(kt % 3) * 8192];
        const unsigned short* sB = &lds[24576 + (kt & 1) * 4096];
#pragma unroll
        for (int n = 0; n < 4; ++n) {
            int rl = wn * 64 + n * 16 + l15;
            bfr[n] = *(const bf16x8*)&sB[(rl * 4 + (q ^ ((rl >> 1) & 3))) * 8];
        }
#pragma unroll
        for (int mg = 0; mg < 2; ++mg) {
#pragma unroll
            for (int mf = 0; mf < 4; ++mf) {
                int rl = wm * 128 + (mg * 4 + mf) * 16 + l15;
                af[mf] = *(const bf16x8*)&sA[(rl * 4 + (q ^ ((rl >> 1) & 3))) * 8];
            }
            __builtin_amdgcn_s_setprio(1);
#pragma unroll
            for (int mf = 0; mf < 4; ++mf)
#pragma unroll
                for (int n = 0; n < 4; ++n)
                    acc[mg * 4 + mf][n] = __builtin_amdgcn_mfma_f32_16x16x32_bf16(
                        af[mf], bfr[n], acc[mg * 4 + mf][n], 0, 0, 0);
            __builtin_amdgcn_s_setprio(0);
        }

        if (kt < 15) BCVW((kt + 1) % 3, kt + 1);   // write next B into opposite parity
        if (kt <= 12) BLOAD((kt + 3) % 3, kt + 3); // issue order: B first...
        if (kt <= 13) ALOAD(kt + 2);               // ...then A (ledger invariant)
        LGKM0;                                     // B ds_writes visible before barrier
        __builtin_amdgcn_s_barrier(); FENCE;
    }
#undef BLOAD
#undef ALOAD
#undef BCVW

    // ---- epilogue: per-row sum(exp)/sum(logit); shfl over l15; [256][2] LDS; atomics ----
    __syncthreads();
    float* redE = (float*)lds;           // [256][2]
    float* redL = redE + 512;            // [256][2]
    float biasv[4];
#pragma unroll
    for (int n = 0; n < 4; ++n) {
        int cc = cbase + wn * 64 + n * 16 + l15;
        biasv[n] = bias[cc < KC ? cc : KC - 1];
    }
#pragma unroll
    for (int m = 0; m < 8; ++m) {
#pragma unroll
        for (int r2 = 0; r2 < 4; ++r2) {
            float pe = 0.f, pl = 0.f;
#pragma unroll
            for (int n = 0; n < 4; ++n) {
                int cc = cbase + wn * 64 + n * 16 + l15;
                if (cc < KC) {
                    float lg = acc[m][n][r2] + biasv[n];
                    pe += __expf(lg);
                    pl += lg;
                }
            }
#pragma unroll
            for (int o = 1; o < 16; o <<= 1) {
                pe += __shfl_xor(pe, o);
                pl += __shfl_xor(pl, o);
            }
            if (l15 == 0) {
                int rowl = wm * 128 + m * 16 + q * 4 + r2;
                redE[rowl * 2 + wn] = pe;
                redL[rowl * 2 + wn] = pl;
            }
        }
    }
    __syncthreads();
    if (tid < 256) {
        float se = redE[tid * 2] + redE[tid * 2 + 1];
        float sl = redL[tid * 2] + redL[tid * 2 + 1];
        atomicAdd(&ws[rowbase + tid], se);
        atomicAdd(&ws[B + rowbase + tid], (EPSSM / (float)KC) * sl);
    }
}

// ---------------- final combine ----------------
__global__ __launch_bounds__(1024) void final_kernel(const float* __restrict__ ws,
                                                     float* __restrict__ out) {
    const float* sumexp = ws;
    const float* lin = ws + B;
    const int* apbits = (const int*)(ws + 2 * B);
    const int* anbits = (const int*)(ws + 3 * B);
    int i = threadIdx.x;
    float ce = logf(sumexp[i]) - lin[i];
    float ap = __int_as_float(apbits[i]);
    float an = __int_as_float(anbits[i]);
    float v = ce + fmaxf(ap - an + MARGIN, 0.f);
    for (int o = 32; o >= 1; o >>= 1) v += __shfl_xor(v, o);
    __shared__ float red[16];
    int wid = threadIdx.x >> 6, lane = threadIdx.x & 63;
    if (lane == 0) red[wid] = v;
    __syncthreads();
    if (threadIdx.x == 0) {
        float s = 0.f;
#pragma unroll
        for (int w = 0; w < 16; ++w) s += red[w];
        out[0] = s / (float)B;
    }
}

extern "C" void kernel_launch(void* const* d_in, const int* in_sizes, int n_in,
                              void* d_out, int out_size, void* d_ws, size_t ws_size,
                              hipStream_t stream) {
    const float* x = (const float*)d_in[0];
    const float* W = (const float*)d_in[1];
    const float* bias = (const float*)d_in[2];
    const int* labels = (const int*)d_in[3];
    float* out = (float*)d_out;
    float* ws = (float*)d_ws;

    unsigned short* xp = (unsigned short*)((char*)d_ws + 16384);   // 1MB packed x

    init_ws<<<16, 256, 0, stream>>>(ws);
    prep_kernel<<<768, 256, 0, stream>>>(x, W, bias, labels, ws, xp);
    ce_gemm_r<<<8 * (NCP_PAD / 8) * 4, 256, 0, stream>>>(xp, W, bias, ws);
    final_kernel<<<1, 1024, 0, stream>>>(ws, out);
}